// Round 10
// baseline (1363.270 us; speedup 1.0000x reference)
//
#include <hip/hip_runtime.h>

#define V 30000
#define E 100
#define H 100
#define T 9
#define B 256
#define S 512

typedef float v2f __attribute__((ext_vector_type(2)));

__device__ __forceinline__ float fast_rcp(float x) { return __builtin_amdgcn_rcpf(x); }

template <int PAT>
__device__ __forceinline__ float dpp_mov(float x) {
  int t = __builtin_amdgcn_update_dpp(0, __builtin_bit_cast(int, x), PAT, 0xF, 0xF, true);
  return __builtin_bit_cast(float, t);
}
// DPP ctrl: 0xB1 quad[1,0,3,2]=xor1; 0x4E quad[2,3,0,1]=xor2; 0x128 row_ror:8=xor8 (within 16-row)

__device__ __forceinline__ void barrier_lds_only() {
  __asm__ volatile("s_waitcnt lgkmcnt(0)\n\ts_barrier" ::: "memory");
}

// ---------------------------------------------------------------------------
// Kernel 1: P_d = embed @ Wih_d^T + b_d, columns permuted so the LSTM's
// coalesced gather column == tid under the (pair p, slot e) lane mapping:
//   o = q*100+u; p=u>>1, u''=u&1, s=p&1, P2=p>>1, w=P2>>2, r=P2&3
//   col = (w<<6) | (r<<4) | (u''<<3) | (s<<2) | q
// LDE=80: staging-write bank stride 16 -> 2-way conflict (free); 72 gave 16-way.
// ---------------------------------------------------------------------------
#define LDE 80

__global__ __launch_bounds__(256) void precompute_P(
    const float* __restrict__ embed,
    const float* __restrict__ Wih_f, const float* __restrict__ b_f,
    const float* __restrict__ Wih_b, const float* __restrict__ b_b,
    float* __restrict__ Pf, float* __restrict__ Pb)
{
  __shared__ __align__(16) float eT[100 * LDE];
  __shared__ __align__(16) float wT[100 * LDE];
  int tid = threadIdx.x;
  int o0 = blockIdx.x * 64;
  int v0 = blockIdx.y * 64;

  for (int idx = tid; idx < 64 * 100; idx += 256) {
    int k = idx % 100, vi = idx / 100;
    int v = v0 + vi;
    eT[k * LDE + vi] = (v < V) ? embed[v * E + k] : 0.0f;
  }
  for (int idx = tid; idx < 64 * 100; idx += 256) {
    int k = idx % 100, oi = idx / 100;
    int o = o0 + oi;
    float val = 0.0f;
    if (o < 400) val = Wih_f[o * E + k];
    else if (o < 800) val = Wih_b[(o - 400) * E + k];
    wT[k * LDE + oi] = val;
  }
  __syncthreads();

  int tx = tid & 15, ty = tid >> 4;
  int vi0 = ty * 4, oi0 = tx * 4;
  float acc[4][4];
#pragma unroll
  for (int i = 0; i < 4; i++)
#pragma unroll
    for (int j = 0; j < 4; j++) acc[i][j] = 0.f;

  for (int k = 0; k < 100; k++) {
    float4 ev = *(const float4*)&eT[k * LDE + vi0];
    float4 wv = *(const float4*)&wT[k * LDE + oi0];
    float e[4] = {ev.x, ev.y, ev.z, ev.w};
    float w[4] = {wv.x, wv.y, wv.z, wv.w};
#pragma unroll
    for (int i = 0; i < 4; i++)
#pragma unroll
      for (int j = 0; j < 4; j++) acc[i][j] += e[i] * w[j];
  }

  for (int i = 0; i < 4; i++) {
    int v = v0 + vi0 + i;
    if (v >= V) break;
    for (int j = 0; j < 4; j++) {
      int o = o0 + oi0 + j;
      if (o >= 800) continue;
      int oo = (o < 400) ? o : (o - 400);
      int q = oo / 100, u = oo % 100;
      int p = u >> 1, u2 = u & 1;
      int s2 = p & 1, P2 = p >> 1;
      int wv_ = P2 >> 2, r_ = P2 & 3;
      int col = (wv_ << 6) | (r_ << 4) | (u2 << 3) | (s2 << 2) | q;
      float bias = (o < 400) ? b_f[oo] : b_b[oo];
      float* dst = (o < 400) ? Pf : Pb;
      dst[(size_t)v * 400 + col] = acc[i][j] + bias;
    }
  }
}

// ---------------------------------------------------------------------------
// Kernel 2: LSTM recurrence, G=8 layout. One (dir,row) chain per block;
// 512 blocks, 512 threads (8 waves), 2 blocks/CU.
//   mv thread tid<400: lane bits -> q=lane&3, s=(lane>>2)&1, u''=(lane>>3)&1,
//   r=(lane>>4)&3; pair p=(wave*4+r)*2+s; slot e = q | (u''<<2).
//   Thread computes 8 gate-partials (2 units x 4 gates) over K-chunk
//   [12e,12e+12) (+k=96+e for e<4): ONE set of 3 h-float4 reads feeds 48
//   pk_fma -> DS reads per chain-step drop ~52 -> ~33 wave-instr (the
//   measured bottleneck). 3-stage all-DPP butterfly reduce-scatter
//   (xor1 quad, xor2 quad, xor8 row_ror:8) lands slot e on lane e; own-gate
//   activation; quad broadcast; redundant c/h update; q==0 lanes write h.
//   em wave (tid 448..483): R7 structure, weights ALIASED into W (single
//   live range with Whh weights).
// ---------------------------------------------------------------------------
__global__ __attribute__((amdgpu_flat_work_group_size(512, 512), amdgpu_waves_per_eu(4, 4)))
void lstm_kernel(
    const int* __restrict__ x,
    const float* __restrict__ Pf, const float* __restrict__ Pb,
    const float* __restrict__ Whh_f, const float* __restrict__ Whh_b,
    const float* __restrict__ Wlin,
    float* __restrict__ em_f, float* __restrict__ em_b)
{
  __shared__ __align__(16) float h_lds[2][104];
  __shared__ int   x_lds[S];
  __shared__ float em_lds[S * T];

  int tid = threadIdx.x;
  int dir = blockIdx.x & 1;
  int b   = blockIdx.x >> 1;

  const float* P   = dir ? Pb : Pf;
  const float* Whh = dir ? Whh_b : Whh_f;
  float*       em  = dir ? em_b : em_f;

  int lane = tid & 63;
  int wv   = tid >> 6;
  int q    = lane & 3;
  int s    = (lane >> 2) & 1;
  int u2   = (lane >> 3) & 1;
  int r    = (lane >> 4) & 3;
  int e    = q | (u2 << 2);
  int p    = ((wv * 4 + r) << 1) | s;

  bool is_mv = (tid < 400);
  bool b0 = (lane & 1), b1 = (lane >> 1) & 1, b2 = u2;

  bool is_em = (tid >= 448 && tid < 448 + 36);
  int  et = tid - 448;
  int  etag = et >> 2, ekq = et & 3;

  // own-gate activation constants (gate 2 = tanh, else sigmoid)
  float mexp = (q == 2) ? -2.f : -1.f;
  float sA   = (q == 2) ?  2.f :  1.f;
  float sB   = (q == 2) ? -1.f :  0.f;

  // ---- weights: W[48] v2f (8 slots x 6) + wr8[8] remainders = 104 floats.
  // em wave reuses W[0..5]+wr8[0] (aliased -> one register allocation).
  int pc = is_mv ? p : 0;
  v2f  W[48];
  float wr8[8];
#pragma unroll
  for (int j = 0; j < 8; j++) {
    int o = (j & 3) * 100 + 2 * pc + (j >> 2);
    const float* row = Whh + (size_t)o * 100;
    const float* ch = row + 12 * e;
#pragma unroll
    for (int i = 0; i < 3; i++) {
      float4 t4 = *(const float4*)&ch[4 * i];
      W[j * 6 + 2 * i]     = (v2f){t4.x, t4.y};
      W[j * 6 + 2 * i + 1] = (v2f){t4.z, t4.w};
    }
    wr8[j] = (e < 4) ? row[96 + e] : 0.f;
  }
  if (is_em) {
    const float* row = &Wlin[etag * (2 * H) + dir * H];
    const float* ch = row + 24 * ekq;
#pragma unroll
    for (int i = 0; i < 6; i++) {
      float4 t4 = *(const float4*)&ch[4 * i];
      W[2 * i]     = (v2f){t4.x, t4.y};
      W[2 * i + 1] = (v2f){t4.z, t4.w};
    }
    wr8[0] = row[96 + ekq];
  }

  for (int i = tid; i < 208; i += 512) ((float*)h_lds)[i] = 0.f;
  for (int i = tid; i < S; i += 512) x_lds[i] = x[(size_t)b * S + i];
  float c = 0.f;
  float pre = 0.f;
  if (is_mv) {
    int tt0 = dir ? (S - 1) : 0;
    pre = P[(size_t)x[(size_t)b * S + tt0] * 400 + tid];
  }
  int prev_tt = 0;
  __syncthreads();

  auto step = [&](int bufc, int t) {
    int tt = dir ? (S - 1 - t) : t;
    if (is_mv) {
      float prv = pre;
      if (t + 1 < S) {                    // register prefetch (spans barrier)
        int ttn = dir ? (S - 2 - t) : (t + 1);
        unsigned sxv = __builtin_amdgcn_readfirstlane(x_lds[ttn]);
        pre = (P + (size_t)sxv * 400)[tid];
      }
      const float* hc = &h_lds[bufc][12 * e];
      float4 h40 = *(const float4*)&hc[0];
      float4 h41 = *(const float4*)&hc[4];
      float4 h42 = *(const float4*)&hc[8];
      float hrem = h_lds[bufc][96 + q];
      v2f hl0 = {h40.x, h40.y}, hh0 = {h40.z, h40.w};
      v2f hl1 = {h41.x, h41.y}, hh1 = {h41.z, h41.w};
      v2f hl2 = {h42.x, h42.y}, hh2 = {h42.z, h42.w};

      float pj[8];
#pragma unroll
      for (int j = 0; j < 8; j++) {
        v2f a = {0.f, 0.f};
        a = __builtin_elementwise_fma(W[j * 6 + 0], hl0, a);
        a = __builtin_elementwise_fma(W[j * 6 + 1], hh0, a);
        a = __builtin_elementwise_fma(W[j * 6 + 2], hl1, a);
        a = __builtin_elementwise_fma(W[j * 6 + 3], hh1, a);
        a = __builtin_elementwise_fma(W[j * 6 + 4], hl2, a);
        a = __builtin_elementwise_fma(W[j * 6 + 5], hh2, a);
        pj[j] = fmaf(wr8[j], hrem, a.x + a.y);
      }

      // 3-stage butterfly reduce-scatter: slot e lands on lane e (all DPP)
      float q1[4];
#pragma unroll
      for (int i = 0; i < 4; i++) {
        float keep = b0 ? pj[2 * i + 1] : pj[2 * i];
        float snd  = b0 ? pj[2 * i]     : pj[2 * i + 1];
        q1[i] = keep + dpp_mov<0xB1>(snd);          // xor1 (e-bit0)
      }
      float q2[2];
#pragma unroll
      for (int m = 0; m < 2; m++) {
        float keep = b1 ? q1[2 * m + 1] : q1[2 * m];
        float snd  = b1 ? q1[2 * m]     : q1[2 * m + 1];
        q2[m] = keep + dpp_mov<0x4E>(snd);          // xor2 (e-bit1)
      }
      float keep3 = b2 ? q2[1] : q2[0];
      float snd3  = b2 ? q2[0] : q2[1];
      float g = keep3 + dpp_mov<0x128>(snd3) + prv; // xor8 (e-bit2)

      // own-gate activation
      float ex  = __expf(mexp * g);
      float act = fmaf(sA, fast_rcp(1.f + ex), sB);

      // quad broadcast: lanes of a quad hold gates 0..3 of unit 2p+b2
      float gi = dpp_mov<0x00>(act);
      float gf = dpp_mov<0x55>(act);
      float tg = dpp_mov<0xAA>(act);
      float go = dpp_mov<0xFF>(act);

      c = fmaf(gf, c, gi * tg);
      float th = fmaf(2.f, fast_rcp(1.f + __expf(-2.f * c)), -1.f);
      if (q == 0) h_lds[bufc ^ 1][2 * p + b2] = go * th;
    } else if (is_em && t > 0) {
      const float* hq = &h_lds[bufc][24 * ekq];
      v2f a = {0.f, 0.f};
#pragma unroll
      for (int i = 0; i < 6; i++) {
        float4 h4 = *(const float4*)&hq[4 * i];
        a = __builtin_elementwise_fma(W[2 * i], (v2f){h4.x, h4.y}, a);
        a = __builtin_elementwise_fma(W[2 * i + 1], (v2f){h4.z, h4.w}, a);
      }
      float hr = h_lds[bufc][96 + ekq];
      float pv = fmaf(wr8[0], hr, a.x + a.y);
      pv += dpp_mov<0xB1>(pv);
      pv += dpp_mov<0x4E>(pv);
      if (ekq == 0) em_lds[prev_tt * T + etag] = pv;
    }
    barrier_lds_only();
    prev_tt = tt;
  };

  for (int t = 0; t < S; t += 2) {
    step(0, t);
    step(1, t + 1);
  }

  if (is_em) {   // final step's projection (h(S-1) in h_lds[0])
    const float* hq = &h_lds[0][24 * ekq];
    v2f a = {0.f, 0.f};
#pragma unroll
    for (int i = 0; i < 6; i++) {
      float4 h4 = *(const float4*)&hq[4 * i];
      a = __builtin_elementwise_fma(W[2 * i], (v2f){h4.x, h4.y}, a);
      a = __builtin_elementwise_fma(W[2 * i + 1], (v2f){h4.z, h4.w}, a);
    }
    float hr = h_lds[0][96 + ekq];
    float pv = fmaf(wr8[0], hr, a.x + a.y);
    pv += dpp_mov<0xB1>(pv);
    pv += dpp_mov<0x4E>(pv);
    if (ekq == 0) em_lds[prev_tt * T + etag] = pv;
  }
  __syncthreads();

  float* dst = em + (size_t)b * S * T;
  for (int i = tid; i < S * T; i += 512) dst[i] = em_lds[i];
}

// ---------------------------------------------------------------------------
// Kernel 3: Viterbi (R7 version, verified absmax 0).
// ---------------------------------------------------------------------------
__global__ __launch_bounds__(64) void viterbi_kernel(
    const float* __restrict__ em_f, const float* __restrict__ em_b,
    const float* __restrict__ blin, const float* __restrict__ start,
    const float* __restrict__ trans, const float* __restrict__ endv,
    float* __restrict__ out)
{
  __shared__ float ev[S * 12];
  __shared__ unsigned char bp[S * T];
  int b = blockIdx.x;
  int lane = threadIdx.x;
  bool act = (lane < T);
  int tag = act ? lane : 0;

  const float* ef = em_f + (size_t)b * S * T;
  const float* eb = em_b + (size_t)b * S * T;
  for (int i = lane; i < S * T; i += 64) {
    int t = i / 9, tg = i - t * 9;
    ev[t * 12 + tg] = ef[i] + eb[i] + blin[tg];
  }
  __syncthreads();

  float tc[T] = {};
  float en = 0.f;
  float score = -1e30f;
  if (act) {
    for (int p = 0; p < T; p++) tc[p] = trans[p * T + tag];
    en = endv[tag];
    score = start[tag] + ev[tag];
  }

  for (int t = 1; t < S; t++) {
    float emv = act ? ev[t * 12 + tag] : 0.f;

    float sv[T];
#pragma unroll
    for (int p = 0; p < T; p++) sv[p] = __shfl(score, p);

    float best = sv[0] + tc[0]; int bestp = 0;
#pragma unroll
    for (int p = 1; p < T; p++) {
      float cand = sv[p] + tc[p];
      if (cand > best) { best = cand; bestp = p; }
    }
    if (act) {
      score = best + emv;
      bp[t * T + tag] = (unsigned char)bestp;
    }
  }
  if (act) score += en;
  __syncthreads();

  float sv[T];
#pragma unroll
  for (int p = 0; p < T; p++) sv[p] = __shfl(score, p);
  float bs = sv[0]; int last = 0;
#pragma unroll
  for (int p = 1; p < T; p++) {
    if (sv[p] > bs) { bs = sv[p]; last = p; }
  }

  if (lane == 0) {
    out[(size_t)B * S + b] = bs;
    int cur = last;
    out[(size_t)b * S + (S - 1)] = (float)cur;
    for (int t = S - 1; t >= 1; t--) {
      cur = bp[t * T + cur];
      out[(size_t)b * S + (t - 1)] = (float)cur;
    }
  }
}

// ---------------------------------------------------------------------------
extern "C" void kernel_launch(void* const* d_in, const int* in_sizes, int n_in,
                              void* d_out, int out_size, void* d_ws, size_t ws_size,
                              hipStream_t stream)
{
  const int*   x     = (const int*)d_in[0];
  const float* embed = (const float*)d_in[2];
  const float* Wih_f = (const float*)d_in[3];
  const float* Whh_f = (const float*)d_in[4];
  const float* b_f   = (const float*)d_in[5];
  const float* Wih_b = (const float*)d_in[6];
  const float* Whh_b = (const float*)d_in[7];
  const float* b_b   = (const float*)d_in[8];
  const float* Wlin  = (const float*)d_in[9];
  const float* blin  = (const float*)d_in[10];
  const float* start = (const float*)d_in[11];
  const float* trans = (const float*)d_in[12];
  const float* endv  = (const float*)d_in[13];
  float* out = (float*)d_out;

  char* ws = (char*)d_ws;
  float* Pf   = (float*)ws;  ws += (size_t)V * 400 * sizeof(float);
  float* Pb   = (float*)ws;  ws += (size_t)V * 400 * sizeof(float);
  float* emf  = (float*)ws;  ws += (size_t)B * S * T * sizeof(float);
  float* emb_ = (float*)ws;  ws += (size_t)B * S * T * sizeof(float);

  precompute_P<<<dim3(13, 469), 256, 0, stream>>>(embed, Wih_f, b_f, Wih_b, b_b, Pf, Pb);
  lstm_kernel<<<dim3(512), 512, 0, stream>>>(x, Pf, Pb, Whh_f, Whh_b, Wlin, emf, emb_);
  viterbi_kernel<<<dim3(256), 64, 0, stream>>>(emf, emb_, blin, start, trans, endv, out);
}

// Round 11
// 998.382 us; speedup vs baseline: 1.3655x; 1.3655x over previous
//
#include <hip/hip_runtime.h>

#define V 30000
#define E 100
#define H 100
#define T 9
#define B 256
#define S 512

typedef float v2f __attribute__((ext_vector_type(2)));

__device__ __forceinline__ float fast_rcp(float x) { return __builtin_amdgcn_rcpf(x); }

template <int PAT>
__device__ __forceinline__ float dpp_mov(float x) {
  int t = __builtin_amdgcn_update_dpp(0, __builtin_bit_cast(int, x), PAT, 0xF, 0xF, true);
  return __builtin_bit_cast(float, t);
}

__device__ __forceinline__ void barrier_lds_only() {
  __asm__ volatile("s_waitcnt lgkmcnt(0)\n\ts_barrier" ::: "memory");
}

// ---------------------------------------------------------------------------
// Kernel 1: P_d = embed @ Wih_d^T + b_d, PERMUTED columns col = 4*u + q
// (u = unit, q = gate) so the LSTM gather column == tid.
// Tile = 16 units x 4 gates (64 outputs) x 64 vocab rows; thread (tx,ty)
// owns unit ut0+tx, gates 0..3 -> the permuted store is ONE coalesced
// float4 per row (R7 version did 16 scattered scalar stores).
// ---------------------------------------------------------------------------
#define LDE 80   // bank stride 16 -> 2-way (free)

__global__ __launch_bounds__(256) void precompute_P(
    const float* __restrict__ embed,
    const float* __restrict__ Wih_f, const float* __restrict__ b_f,
    const float* __restrict__ Wih_b, const float* __restrict__ b_b,
    float* __restrict__ Pf, float* __restrict__ Pb)
{
  __shared__ __align__(16) float eT[100 * LDE];  // eT[k][vi]
  __shared__ __align__(16) float wT[100 * LDE];  // wT[k][oi], oi = 4*ul + q
  int tid = threadIdx.x;
  int d   = (blockIdx.x >= 7);
  int ut0 = (blockIdx.x - (d ? 7 : 0)) * 16;
  int v0  = blockIdx.y * 64;

  const float* Wih  = d ? Wih_b : Wih_f;
  const float* bias = d ? b_b : b_f;
  float*       dst  = d ? Pb : Pf;

  for (int idx = tid; idx < 64 * 100; idx += 256) {
    int k = idx % 100, vi = idx / 100;
    int v = v0 + vi;
    eT[k * LDE + vi] = (v < V) ? embed[v * E + k] : 0.0f;
  }
  for (int idx = tid; idx < 64 * 100; idx += 256) {
    int k = idx % 100, oi = idx / 100;
    int ul = oi >> 2, q = oi & 3;
    int u = ut0 + ul;
    wT[k * LDE + oi] = (u < 100) ? Wih[(size_t)(q * 100 + u) * E + k] : 0.0f;
  }
  __syncthreads();

  int tx = tid & 15, ty = tid >> 4;
  int vi0 = ty * 4, oi0 = tx * 4;
  float acc[4][4];
#pragma unroll
  for (int i = 0; i < 4; i++)
#pragma unroll
    for (int j = 0; j < 4; j++) acc[i][j] = 0.f;

  for (int k = 0; k < 100; k++) {
    float4 ev = *(const float4*)&eT[k * LDE + vi0];
    float4 wv = *(const float4*)&wT[k * LDE + oi0];
    float e[4] = {ev.x, ev.y, ev.z, ev.w};
    float w[4] = {wv.x, wv.y, wv.z, wv.w};
#pragma unroll
    for (int i = 0; i < 4; i++)
#pragma unroll
      for (int j = 0; j < 4; j++) acc[i][j] += e[i] * w[j];
  }

  int u = ut0 + tx;
  if (u < 100) {
    float b0 = bias[u], b1 = bias[100 + u], b2 = bias[200 + u], b3 = bias[300 + u];
#pragma unroll
    for (int i = 0; i < 4; i++) {
      int v = v0 + vi0 + i;
      if (v >= V) break;
      float4 o4 = make_float4(acc[i][0] + b0, acc[i][1] + b1,
                              acc[i][2] + b2, acc[i][3] + b3);
      *(float4*)&dst[(size_t)v * 400 + 4 * u] = o4;   // coalesced, 16B aligned
    }
  }
}

// ---------------------------------------------------------------------------
// Kernel 2: LSTM recurrence (R7 structure + folds). One (dir,row) chain per
// block; 512 blocks, block = 448 threads (7 waves), 2 blocks/CU.
//   tid<400: matvec, og=tid>>2 (unit), kq=tid&3 (K-quarter 24 + remainder).
//     DPP quad reduce-scatter -> own-gate activation -> DPP quad broadcast.
//   tid in [400,436): em projection, FOLDED into wave 6's idle lanes
//     (saves the whole 8th wave of R7); em weights ALIASED into W so the
//     kernel-wide live weight set stays ~100 floats.
//   x read via SCALAR load (wave-uniform index), prefetched 2 steps ahead
//     (removes the x_lds DS broadcast + readfirstlane of R7).
// ONE lgkm-only barrier per step.
// ---------------------------------------------------------------------------
__global__ __attribute__((amdgpu_flat_work_group_size(448, 448), amdgpu_waves_per_eu(4, 4)))
void lstm_kernel(
    const int* __restrict__ x,
    const float* __restrict__ Pf, const float* __restrict__ Pb,
    const float* __restrict__ Whh_f, const float* __restrict__ Whh_b,
    const float* __restrict__ Wlin,
    float* __restrict__ em_f, float* __restrict__ em_b)
{
  __shared__ __align__(16) float h_lds[2][104];
  __shared__ float em_lds[S * T];

  int tid = threadIdx.x;
  int dir = blockIdx.x & 1;
  int b   = blockIdx.x >> 1;

  const float* P   = dir ? Pb : Pf;
  const float* Whh = dir ? Whh_b : Whh_f;
  float*       em  = dir ? em_b : em_f;
  const int*   x_row = x + (size_t)b * S;

  bool is_mv = (tid < 400);
  int  og = tid >> 2, kq = tid & 3;
  bool lo2  = (kq < 2);
  bool oddl = (kq & 1);

  bool is_em = (tid >= 400 && tid < 436);
  int  et = tid - 400;
  int  etag = et >> 2, ekq = et & 3;

  float mexp = (kq == 2) ? -2.f : -1.f;
  float sA   = (kq == 2) ?  2.f :  1.f;
  float sB   = (kq == 2) ? -1.f :  0.f;

  // ---- weights: W[48] v2f + wr4[4] = 100 floats, em ALIASED into W[0..11]
  v2f  W[48];
  float wr4[4];
  if (is_mv) {
#pragma unroll
    for (int q = 0; q < 4; q++) {
      const float* row = &Whh[(size_t)(q * 100 + og) * 100];
#pragma unroll
      for (int i = 0; i < 6; i++) {
        float4 t4 = *(const float4*)&row[24 * kq + 4 * i];
        W[q * 12 + 2 * i]     = (v2f){t4.x, t4.y};
        W[q * 12 + 2 * i + 1] = (v2f){t4.z, t4.w};
      }
      wr4[q] = row[96 + kq];
    }
  } else if (is_em) {
    const float* row = &Wlin[etag * (2 * H) + dir * H];
#pragma unroll
    for (int i = 0; i < 6; i++) {
      float4 t4 = *(const float4*)&row[24 * ekq + 4 * i];
      W[2 * i]     = (v2f){t4.x, t4.y};
      W[2 * i + 1] = (v2f){t4.z, t4.w};
    }
    wr4[0] = row[96 + ekq];
  }

  for (int i = tid; i < 208; i += 448) ((float*)h_lds)[i] = 0.f;
  float c = 0.f;
  float pre = 0.f;
  int tt0 = dir ? (S - 1) : 0;
  if (is_mv) pre = P[(size_t)x_row[tt0] * 400 + tid];
  int xv_next = x_row[dir ? (S - 2) : 1];   // x for step 1 (scalar, prefetched)
  int prev_tt = 0;
  __syncthreads();

  auto step = [&](int bufc, int t) {
    int tt = dir ? (S - 1 - t) : t;
    if (is_mv) {
      float prv = pre;
      if (t + 1 < S) {
        pre = P[(size_t)xv_next * 400 + tid];   // reg prefetch, spans barrier
      }
      const float* hq = &h_lds[bufc][24 * kq];
      v2f a0 = {0.f, 0.f}, a1 = {0.f, 0.f}, a2 = {0.f, 0.f}, a3 = {0.f, 0.f};
#pragma unroll
      for (int i = 0; i < 6; i++) {
        float4 h4 = *(const float4*)&hq[4 * i];
        v2f hlo = {h4.x, h4.y}, hhi = {h4.z, h4.w};
        a0 = __builtin_elementwise_fma(W[0 * 12 + 2 * i], hlo, a0);
        a0 = __builtin_elementwise_fma(W[0 * 12 + 2 * i + 1], hhi, a0);
        a1 = __builtin_elementwise_fma(W[1 * 12 + 2 * i], hlo, a1);
        a1 = __builtin_elementwise_fma(W[1 * 12 + 2 * i + 1], hhi, a1);
        a2 = __builtin_elementwise_fma(W[2 * 12 + 2 * i], hlo, a2);
        a2 = __builtin_elementwise_fma(W[2 * 12 + 2 * i + 1], hhi, a2);
        a3 = __builtin_elementwise_fma(W[3 * 12 + 2 * i], hlo, a3);
        a3 = __builtin_elementwise_fma(W[3 * 12 + 2 * i + 1], hhi, a3);
      }
      float hr = h_lds[bufc][96 + kq];
      float p0 = fmaf(wr4[0], hr, a0.x + a0.y);
      float p1 = fmaf(wr4[1], hr, a1.x + a1.y);
      float p2 = fmaf(wr4[2], hr, a2.x + a2.y);
      float p3 = fmaf(wr4[3], hr, a3.x + a3.y);

      float u  = lo2 ? p2 : p0;
      float v  = lo2 ? p3 : p1;
      float ru = dpp_mov<0x4E>(u);
      float rv = dpp_mov<0x4E>(v);
      float A  = (lo2 ? p0 : p2) + ru;
      float Bv = (lo2 ? p1 : p3) + rv;
      float wv = oddl ? A : Bv;
      float rw = dpp_mov<0xB1>(wv);
      float g  = (oddl ? Bv : A) + rw + prv;

      float e   = __expf(mexp * g);
      float act = fmaf(sA, fast_rcp(1.f + e), sB);

      float gi = dpp_mov<0x00>(act);
      float gf = dpp_mov<0x55>(act);
      float tg = dpp_mov<0xAA>(act);
      float go = dpp_mov<0xFF>(act);

      c = fmaf(gf, c, gi * tg);
      float th = fmaf(2.f, fast_rcp(1.f + __expf(-2.f * c)), -1.f);
      if (kq == 0) h_lds[bufc ^ 1][og] = go * th;
    } else if (is_em && t > 0) {
      const float* hq = &h_lds[bufc][24 * ekq];
      v2f a = {0.f, 0.f};
#pragma unroll
      for (int i = 0; i < 6; i++) {
        float4 h4 = *(const float4*)&hq[4 * i];
        a = __builtin_elementwise_fma(W[2 * i], (v2f){h4.x, h4.y}, a);
        a = __builtin_elementwise_fma(W[2 * i + 1], (v2f){h4.z, h4.w}, a);
      }
      float hr = h_lds[bufc][96 + ekq];
      float pv = fmaf(wr4[0], hr, a.x + a.y);
      pv += dpp_mov<0xB1>(pv);
      pv += dpp_mov<0x4E>(pv);
      if (ekq == 0) em_lds[prev_tt * T + etag] = pv;
    }
    // scalar x prefetch for step t+2 (uniform -> s_load, fully hidden)
    if (t + 2 < S) xv_next = x_row[dir ? (S - 3 - t) : (t + 2)];
    barrier_lds_only();
    prev_tt = tt;
  };

  for (int t = 0; t < S; t += 2) {
    step(0, t);
    step(1, t + 1);
  }

  if (is_em) {   // final step's projection (h(S-1) in h_lds[0])
    const float* hq = &h_lds[0][24 * ekq];
    v2f a = {0.f, 0.f};
#pragma unroll
    for (int i = 0; i < 6; i++) {
      float4 h4 = *(const float4*)&hq[4 * i];
      a = __builtin_elementwise_fma(W[2 * i], (v2f){h4.x, h4.y}, a);
      a = __builtin_elementwise_fma(W[2 * i + 1], (v2f){h4.z, h4.w}, a);
    }
    float hr = h_lds[0][96 + ekq];
    float pv = fmaf(wr4[0], hr, a.x + a.y);
    pv += dpp_mov<0xB1>(pv);
    pv += dpp_mov<0x4E>(pv);
    if (ekq == 0) em_lds[prev_tt * T + etag] = pv;
  }
  __syncthreads();

  float* dst = em + (size_t)b * S * T;
  for (int i = tid; i < S * T; i += 448) dst[i] = em_lds[i];
}

// ---------------------------------------------------------------------------
// Kernel 3: Viterbi (R7 version, verified absmax 0).
// ---------------------------------------------------------------------------
__global__ __launch_bounds__(64) void viterbi_kernel(
    const float* __restrict__ em_f, const float* __restrict__ em_b,
    const float* __restrict__ blin, const float* __restrict__ start,
    const float* __restrict__ trans, const float* __restrict__ endv,
    float* __restrict__ out)
{
  __shared__ float ev[S * 12];
  __shared__ unsigned char bp[S * T];
  int b = blockIdx.x;
  int lane = threadIdx.x;
  bool act = (lane < T);
  int tag = act ? lane : 0;

  const float* ef = em_f + (size_t)b * S * T;
  const float* eb = em_b + (size_t)b * S * T;
  for (int i = lane; i < S * T; i += 64) {
    int t = i / 9, tg = i - t * 9;
    ev[t * 12 + tg] = ef[i] + eb[i] + blin[tg];
  }
  __syncthreads();

  float tc[T] = {};
  float en = 0.f;
  float score = -1e30f;
  if (act) {
    for (int p = 0; p < T; p++) tc[p] = trans[p * T + tag];
    en = endv[tag];
    score = start[tag] + ev[tag];
  }

  for (int t = 1; t < S; t++) {
    float emv = act ? ev[t * 12 + tag] : 0.f;

    float sv[T];
#pragma unroll
    for (int p = 0; p < T; p++) sv[p] = __shfl(score, p);

    float best = sv[0] + tc[0]; int bestp = 0;
#pragma unroll
    for (int p = 1; p < T; p++) {
      float cand = sv[p] + tc[p];
      if (cand > best) { best = cand; bestp = p; }
    }
    if (act) {
      score = best + emv;
      bp[t * T + tag] = (unsigned char)bestp;
    }
  }
  if (act) score += en;
  __syncthreads();

  float sv[T];
#pragma unroll
  for (int p = 0; p < T; p++) sv[p] = __shfl(score, p);
  float bs = sv[0]; int last = 0;
#pragma unroll
  for (int p = 1; p < T; p++) {
    if (sv[p] > bs) { bs = sv[p]; last = p; }
  }

  if (lane == 0) {
    out[(size_t)B * S + b] = bs;
    int cur = last;
    out[(size_t)b * S + (S - 1)] = (float)cur;
    for (int t = S - 1; t >= 1; t--) {
      cur = bp[t * T + cur];
      out[(size_t)b * S + (t - 1)] = (float)cur;
    }
  }
}

// ---------------------------------------------------------------------------
extern "C" void kernel_launch(void* const* d_in, const int* in_sizes, int n_in,
                              void* d_out, int out_size, void* d_ws, size_t ws_size,
                              hipStream_t stream)
{
  const int*   x     = (const int*)d_in[0];
  const float* embed = (const float*)d_in[2];
  const float* Wih_f = (const float*)d_in[3];
  const float* Whh_f = (const float*)d_in[4];
  const float* b_f   = (const float*)d_in[5];
  const float* Wih_b = (const float*)d_in[6];
  const float* Whh_b = (const float*)d_in[7];
  const float* b_b   = (const float*)d_in[8];
  const float* Wlin  = (const float*)d_in[9];
  const float* blin  = (const float*)d_in[10];
  const float* start = (const float*)d_in[11];
  const float* trans = (const float*)d_in[12];
  const float* endv  = (const float*)d_in[13];
  float* out = (float*)d_out;

  char* ws = (char*)d_ws;
  float* Pf   = (float*)ws;  ws += (size_t)V * 400 * sizeof(float);
  float* Pb   = (float*)ws;  ws += (size_t)V * 400 * sizeof(float);
  float* emf  = (float*)ws;  ws += (size_t)B * S * T * sizeof(float);
  float* emb_ = (float*)ws;  ws += (size_t)B * S * T * sizeof(float);

  precompute_P<<<dim3(14, 469), 256, 0, stream>>>(embed, Wih_f, b_f, Wih_b, b_b, Pf, Pb);
  lstm_kernel<<<dim3(512), 448, 0, stream>>>(x, Pf, Pb, Whh_f, Whh_b, Wlin, emf, emb_);
  viterbi_kernel<<<dim3(256), 64, 0, stream>>>(emf, emb_, blin, start, trans, endv, out);
}